// Round 3
// baseline (240.941 us; speedup 1.0000x reference)
//
#include <hip/hip_runtime.h>
#include <hip/hip_bf16.h>
#include <stdint.h>

typedef uint16_t u16;
typedef uint32_t u32;
typedef __attribute__((ext_vector_type(8))) short bv8;    // 8 x bf16 (i16 bits), 4 VGPR
typedef __attribute__((ext_vector_type(4))) float f32x4;
typedef __attribute__((ext_vector_type(2))) u32 u32x2;

#define MFMA(a,b,c) __builtin_amdgcn_mfma_f32_16x16x32_bf16((a),(b),(c),0,0,0)

__device__ __forceinline__ float bf2f(u16 v){ u32 x=(u32)v<<16; float f; __builtin_memcpy(&f,&x,4); return f; }
__device__ __forceinline__ u16 f2bf(float f){ u32 x; __builtin_memcpy(&x,&f,4); x += 0x7fffu + ((x>>16)&1u); return (u16)(x>>16); }

__device__ __forceinline__ void gl_lds16(const u16* g, u16* l){
  __builtin_amdgcn_global_load_lds((const __attribute__((address_space(1))) u32*)g,
                                   (__attribute__((address_space(3))) u32*)l, 16, 0, 0);
}

// fp32 -> bf16 convert. n8 = elements/8.
__global__ __launch_bounds__(256) void cvt_bf16(const float* __restrict__ src, u16* __restrict__ dst, long n8){
  long i = (long)blockIdx.x*256 + threadIdx.x;
  long stride = (long)gridDim.x*256;
  for(; i<n8; i+=stride){
    f32x4 a = *(const f32x4*)(src + i*8);
    f32x4 b = *(const f32x4*)(src + i*8 + 4);
    bv8 o;
    #pragma unroll
    for(int j=0;j<4;j++) o[j]   = (short)f2bf(a[j]);
    #pragma unroll
    for(int j=0;j<4;j++) o[4+j] = (short)f2bf(b[j]);
    *(bv8*)(dst + i*8) = o;
  }
}

// ---------------------------------------------------------------------------
// C[m,n] = sum_k A[m,k] * B[n,k]   (A: MxK bf16 row-major, B: NxK bf16)
// C written as bf16 (OUTF32=false) or fp32 (OUTF32=true).
// 128x128 tile, BK=64, 4 waves (each 64x64), global_load_lds w/ pre-swizzled src.
// LDS rows: 64 els = 128B = 8 x 16B slots, slot ^= (row&7) -> conflict-free b128.
// ---------------------------------------------------------------------------
template<bool OUTF32>
__global__ __launch_bounds__(256,2) void gemm_bt(const u16* __restrict__ A, const u16* __restrict__ B,
                                                 void* __restrict__ Cv, int M, int N, int K){
  __shared__ __align__(16) u16 As[128*64];
  __shared__ __align__(16) u16 Bs[128*64];
  int nwg = gridDim.x;
  int wg  = (int)blockIdx.x;
  wg = (wg & 7)*(nwg>>3) + (wg>>3);          // XCD swizzle (nwg % 8 == 0 for our launches)
  int nn = N>>7;
  int tm = wg/nn, tn = wg - tm*nn;
  int rowbase = tm<<7, colbase = tn<<7;
  int t = threadIdx.x, lane = t&63, w = t>>6;
  int g = lane>>4, q16 = lane&15;
  int wr = w>>1, wc = w&1;

  f32x4 z = {0.f,0.f,0.f,0.f};
  f32x4 acc[4][4];
  #pragma unroll
  for(int i=0;i<4;i++)
    #pragma unroll
    for(int j=0;j<4;j++) acc[i][j]=z;

  for(int k0=0;k0<K;k0+=64){
    __syncthreads();
    #pragma unroll
    for(int i=0;i<4;i++){
      int s = ((w<<2)+i)*64 + lane;          // 16B slot index 0..1023
      int row = s>>3;
      int ksl = (s&7) ^ (row&7);             // inverse-swizzled global k-slot
      gl_lds16(A + (size_t)(rowbase+row)*K + k0 + ksl*8, (u16*)As + ((w<<2)+i)*512);
      gl_lds16(B + (size_t)(colbase+row)*K + k0 + ksl*8, (u16*)Bs + ((w<<2)+i)*512);
    }
    __syncthreads();
    #pragma unroll
    for(int eks=0;eks<2;eks++){
      bv8 af[4], bfr[4];
      #pragma unroll
      for(int mi=0;mi<4;mi++){
        int row = (wr<<6)+(mi<<4)+q16;
        af[mi] = *(const bv8*)(As + row*64 + ((((eks<<2)|g) ^ (row&7))<<3));
      }
      #pragma unroll
      for(int ni=0;ni<4;ni++){
        int row = (wc<<6)+(ni<<4)+q16;
        bfr[ni] = *(const bv8*)(Bs + row*64 + ((((eks<<2)|g) ^ (row&7))<<3));
      }
      #pragma unroll
      for(int mi=0;mi<4;mi++)
        #pragma unroll
        for(int ni=0;ni<4;ni++)
          acc[mi][ni] = MFMA(af[mi], bfr[ni], acc[mi][ni]);
    }
  }
  #pragma unroll
  for(int mi=0;mi<4;mi++){
    #pragma unroll
    for(int ni=0;ni<4;ni++){
      int row = rowbase + (wr<<6) + (mi<<4) + (g<<2);
      int col = colbase + (wc<<6) + (ni<<4) + q16;
      if(OUTF32){
        float* cp = (float*)Cv + (size_t)row*N + col;
        #pragma unroll
        for(int r=0;r<4;r++) cp[(size_t)r*N] = acc[mi][ni][r];
      } else {
        u16* cp = (u16*)Cv + (size_t)row*N + col;
        #pragma unroll
        for(int r=0;r<4;r++) cp[(size_t)r*N] = f2bf(acc[mi][ni][r]);
      }
    }
  }
}

// ---------------------------------------------------------------------------
// In-place RMSNorm + RoPE on q,k of qkv (B,L,3,H,hd). One wave per row of 64.
// cos/sin/qw/kw are fp32.
// ---------------------------------------------------------------------------
__global__ __launch_bounds__(256) void normrope(u16* __restrict__ qkv, const float* __restrict__ cosT,
                                                const float* __restrict__ sinT, const float* __restrict__ qw,
                                                const float* __restrict__ kw){
  int t = threadIdx.x, lane = t&63, wv = t>>6;
  long gid = (long)blockIdx.x*4 + wv;        // over B*L*2*H = 262144 rows
  int h = (int)(gid & 15);
  int s = (int)((gid>>4) & 1);
  long bl = gid >> 5;                        // 0..8191
  int l = (int)(bl & 1023);
  u16* p = qkv + bl*3072 + s*1024 + h*64 + lane;
  float x = bf2f(*p);
  float ss = x*x;
  #pragma unroll
  for(int m=1;m<64;m<<=1) ss += __shfl_xor(ss, m, 64);
  float nrm = rsqrtf(ss*(1.f/64.f) + 1e-6f);
  float y = x * nrm * (s ? kw[lane] : qw[lane]);
  float other = __shfl_xor(y, 32, 64);
  float rot = (lane<32)? -other : other;     // rotate_half
  int ci = l*64 + lane;
  *p = f2bf(y*cosT[ci] + rot*sinT[ci]);
}

// ---------------------------------------------------------------------------
// Flash attention. Block = 4 waves, each wave owns 16 q rows (BQ=64). KV tile = 128.
// Swapped QK^T: lane holds S^T[kv=mi*16+4g+r][q=lane&15].
// K in LDS (swizzled rows), V^T in LDS (swizzled), P via per-wave swizzled LDS.
// ---------------------------------------------------------------------------
__global__ __launch_bounds__(256,2) void fattn(const u16* __restrict__ qkv, u16* __restrict__ Out){
  __shared__ __align__(16) u16 Ks[128*64];      // [kv][e], slot^=(kv&7)
  __shared__ __align__(16) u16 Vt[64*128];      // [d][kv], slot^=(d&15)
  __shared__ __align__(16) u16 Ps[4*16*128];    // per-wave [q][kv], slot^=(q&7)

  int t = threadIdx.x, lane = t&63, w = t>>6;
  int g = lane>>4, q16 = lane&15;
  int nwg = gridDim.x;
  int bid = (int)blockIdx.x;
  bid = (bid & 7)*(nwg>>3) + (bid>>3);          // XCD swizzle
  int bh = bid >> 4, qt = bid & 15;
  int b = bh >> 4, h = bh & 15;
  const u16* base = qkv + (size_t)b*1024*3072;

  bv8 qf[2];
  {
    const u16* qp = base + (size_t)((qt<<6) + (w<<4) + q16)*3072 + h*64;
    qf[0] = *(const bv8*)(qp + (g<<3));
    qf[1] = *(const bv8*)(qp + 32 + (g<<3));
  }
  f32x4 z = {0.f,0.f,0.f,0.f};
  f32x4 accO[4];
  #pragma unroll
  for(int i=0;i<4;i++) accO[i]=z;
  float m_run = -1e30f, l_run = 0.f;

  for(int kv0=0; kv0<1024; kv0+=128){
    __syncthreads();
    // stage K (global_load_lds, pre-swizzled source)
    #pragma unroll
    for(int i=0;i<4;i++){
      int s = ((w<<2)+i)*64 + lane;
      int row = s>>3;
      int esl = (s&7) ^ (row&7);
      gl_lds16(base + (size_t)(kv0+row)*3072 + 1024 + h*64 + esl*8, (u16*)Ks + ((w<<2)+i)*512);
    }
    // stage V transposed via registers
    {
      int d0 = (t&7)<<3;                     // d block of 8
      int kvr = (t>>3)<<2;                   // 4 kv rows
      const u16* gV = base + (size_t)(kv0+kvr)*3072 + 2048 + h*64 + d0;
      bv8 v0 = *(const bv8*)(gV);
      bv8 v1 = *(const bv8*)(gV + 3072);
      bv8 v2 = *(const bv8*)(gV + 6144);
      bv8 v3 = *(const bv8*)(gV + 9216);
      int slot = kvr>>3, half = (kvr>>2)&1;
      #pragma unroll
      for(int i=0;i<8;i++){
        int d = d0+i;
        u32x2 val;
        val.x = (u32)(u16)v0[i] | ((u32)(u16)v1[i]<<16);
        val.y = (u32)(u16)v2[i] | ((u32)(u16)v3[i]<<16);
        *(u32x2*)((char*)Vt + d*256 + ((slot ^ (d&15))<<4) + (half<<3)) = val;
      }
    }
    __syncthreads();
    // QK^T (swapped): sacc[mi] holds S^T[kv = mi*16+4g+r][q16]
    f32x4 sacc[8];
    #pragma unroll
    for(int i=0;i<8;i++) sacc[i]=z;
    #pragma unroll
    for(int eks=0;eks<2;eks++){
      #pragma unroll
      for(int mi=0;mi<8;mi++){
        int row = (mi<<4) + q16;
        bv8 kf = *(const bv8*)(Ks + row*64 + ((((eks<<2)|g) ^ (row&7))<<3));
        sacc[mi] = MFMA(kf, qf[eks], sacc[mi]);
      }
    }
    // online softmax (per q-row = q16; partners at lane^16, lane^32)
    float rm = -1e30f;
    #pragma unroll
    for(int mi=0;mi<8;mi++)
      #pragma unroll
      for(int r=0;r<4;r++){ float sv = sacc[mi][r]*0.125f; sacc[mi][r]=sv; rm = fmaxf(rm, sv); }
    rm = fmaxf(rm, __shfl_xor(rm,16,64));
    rm = fmaxf(rm, __shfl_xor(rm,32,64));
    float mnew = fmaxf(m_run, rm);
    float fac = __expf(m_run - mnew);
    m_run = mnew;
    float ps = 0.f;
    #pragma unroll
    for(int mi=0;mi<8;mi++){
      u16 b0 = f2bf(__expf(sacc[mi][0]-mnew));
      u16 b1 = f2bf(__expf(sacc[mi][1]-mnew));
      u16 b2 = f2bf(__expf(sacc[mi][2]-mnew));
      u16 b3 = f2bf(__expf(sacc[mi][3]-mnew));
      // accumulate denominator from the bf16-ROUNDED P actually used in PV
      ps += (bf2f(b0)+bf2f(b1)) + (bf2f(b2)+bf2f(b3));
      u32x2 val;
      val.x = (u32)b0 | ((u32)b1<<16);
      val.y = (u32)b2 | ((u32)b3<<16);
      int slot = (mi<<1)|(g>>1);
      *(u32x2*)((char*)Ps + (w<<12) + (q16<<8) + ((slot ^ (q16&7))<<4) + ((g&1)<<3)) = val;
    }
    ps += __shfl_xor(ps,16,64);
    ps += __shfl_xor(ps,32,64);
    l_run = l_run*fac + ps;
    float fr0 = __shfl(fac, (g<<2)|0, 64);
    float fr1 = __shfl(fac, (g<<2)|1, 64);
    float fr2 = __shfl(fac, (g<<2)|2, 64);
    float fr3 = __shfl(fac, (g<<2)|3, 64);
    #pragma unroll
    for(int db=0;db<4;db++){ accO[db][0]*=fr0; accO[db][1]*=fr1; accO[db][2]*=fr2; accO[db][3]*=fr3; }
    // PV: O[q=4g+r][d=db*16+q16] += P * V
    #pragma unroll
    for(int ks=0;ks<4;ks++){
      bv8 pf = *(const bv8*)(Ps + (w<<11) + (q16<<7) + ((((ks<<2)|g) ^ (q16&7))<<3));
      #pragma unroll
      for(int db=0;db<4;db++){
        int dd = (db<<4) + q16;
        bv8 vf = *(const bv8*)(Vt + dd*128 + ((((ks<<2)|g) ^ (dd&15))<<3));
        accO[db] = MFMA(pf, vf, accO[db]);
      }
    }
  }
  // epilogue
  float li0 = 1.f/__shfl(l_run, (g<<2)|0, 64);
  float li1 = 1.f/__shfl(l_run, (g<<2)|1, 64);
  float li2 = 1.f/__shfl(l_run, (g<<2)|2, 64);
  float li3 = 1.f/__shfl(l_run, (g<<2)|3, 64);
  #pragma unroll
  for(int db=0;db<4;db++){
    int qrow = (qt<<6) + (w<<4) + (g<<2);
    size_t o = (size_t)(b*1024 + qrow)*1024 + h*64 + (db<<4) + q16;
    Out[o        ] = f2bf(accO[db][0]*li0);
    Out[o + 1024 ] = f2bf(accO[db][1]*li1);
    Out[o + 2048 ] = f2bf(accO[db][2]*li2);
    Out[o + 3072 ] = f2bf(accO[db][3]*li3);
  }
}

extern "C" void kernel_launch(void* const* d_in, const int* in_sizes, int n_in,
                              void* d_out, int out_size, void* d_ws, size_t ws_size,
                              hipStream_t stream) {
  const float* x      = (const float*)d_in[0];
  const float* cosT   = (const float*)d_in[1];
  const float* sinT   = (const float*)d_in[2];
  const float* w_qkv  = (const float*)d_in[3];
  const float* w_proj = (const float*)d_in[4];
  const float* qw     = (const float*)d_in[5];
  const float* kw     = (const float*)d_in[6];
  float* out = (float*)d_out;

  // ws layout (u16 units): xb is dead after qkv GEMM -> attn aliases it.
  u16* xb     = (u16*)d_ws;                         //  8388608 elems
  u16* wqkvb  = xb     + (size_t) 8388608;          //  3145728
  u16* wprojb = wqkvb  + (size_t) 3145728;          //  1048576
  u16* qkv    = wprojb + (size_t) 1048576;          // 25165824
  u16* attn   = xb;                                 //  8388608 (alias, rewritten each call)

  cvt_bf16<<<2048, 256, 0, stream>>>(x,      xb,     1048576);
  cvt_bf16<<<1536, 256, 0, stream>>>(w_qkv,  wqkvb,   393216);
  cvt_bf16<<< 512, 256, 0, stream>>>(w_proj, wprojb,  131072);

  gemm_bt<false><<<1536, 256, 0, stream>>>(xb, wqkvb, qkv, 8192, 3072, 1024);
  normrope<<<65536, 256, 0, stream>>>(qkv, cosT, sinT, qw, kw);
  fattn   <<<2048, 256, 0, stream>>>(qkv, attn);
  gemm_bt<true><<<512, 256, 0, stream>>>(attn, wprojb, out, 8192, 1024, 1024);
}